// Round 6
// baseline (1746.801 us; speedup 1.0000x reference)
//
#include <hip/hip_runtime.h>
#include <hip/hip_bf16.h>
#include <cstdint>
#include <cstddef>

typedef __attribute__((ext_vector_type(4))) float floatx4;
typedef __attribute__((ext_vector_type(8))) short shortx8;

#define T_SEQ 512
#define NIN   512
#define BATCH 256
#define HID   256
#define G3    768
#define NC    101

static __device__ __forceinline__ unsigned short f2bf(float f){
  unsigned int u = __float_as_uint(f);
  u += 0x7FFFu + ((u >> 16) & 1u);
  return (unsigned short)(u >> 16);
}

// ---------------- Phase A: xg[b*Tc+tt][n] = x[b, t0+tt, :] . Wih[n, :] + bih[n]
#define BM 128
#define BN 128
#define BK 64
#define LDK 72

__global__ __launch_bounds__(256) void gemm_xg(
    const float* __restrict__ x, const float* __restrict__ Wih,
    const float* __restrict__ bih, float* __restrict__ xg,
    int t0, int tcLog2)
{
  __shared__ unsigned short As[BM*LDK];
  __shared__ unsigned short Bs[BN*LDK];
  const int tid  = threadIdx.x;
  const int bn   = blockIdx.x;   // N fastest: 6 consecutive blocks share one x-tile
  const int bm   = blockIdx.y;
  const int w    = tid >> 6;
  const int l    = tid & 63;
  const int lm   = l & 15;
  const int quad = l >> 4;

  const int srow = tid >> 4;
  const int scol = (tid & 15) * 4;
  const int tcMask = (1 << tcLog2) - 1;

  floatx4 acc[2][8];
  #pragma unroll
  for (int mt = 0; mt < 2; ++mt)
    #pragma unroll
    for (int nt = 0; nt < 8; ++nt)
      acc[mt][nt] = (floatx4){0.f, 0.f, 0.f, 0.f};

  for (int kt = 0; kt < NIN / BK; ++kt){
    const int k0 = kt * BK;
    __syncthreads();
    #pragma unroll
    for (int p = 0; p < 8; ++p){
      const int r  = p * 16 + srow;
      const int gm = bm * BM + r;
      const int b  = gm >> tcLog2;
      const int tt = gm & tcMask;
      const float4 xa = *(const float4*)(x + (size_t)(b * T_SEQ + t0 + tt) * NIN + k0 + scol);
      union { unsigned short u[4]; uint2 v; } pa;
      pa.u[0] = f2bf(xa.x); pa.u[1] = f2bf(xa.y); pa.u[2] = f2bf(xa.z); pa.u[3] = f2bf(xa.w);
      *(uint2*)&As[r * LDK + scol] = pa.v;
      const int gn = bn * BN + r;
      const float4 wb = *(const float4*)(Wih + (size_t)gn * NIN + k0 + scol);
      union { unsigned short u[4]; uint2 v; } pb;
      pb.u[0] = f2bf(wb.x); pb.u[1] = f2bf(wb.y); pb.u[2] = f2bf(wb.z); pb.u[3] = f2bf(wb.w);
      *(uint2*)&Bs[r * LDK + scol] = pb.v;
    }
    __syncthreads();
    #pragma unroll
    for (int ks = 0; ks < 2; ++ks){
      const int kk = ks * 32 + quad * 8;
      shortx8 af[2], bfr[8];
      #pragma unroll
      for (int mt = 0; mt < 2; ++mt)
        af[mt] = *(const shortx8*)&As[(w * 32 + mt * 16 + lm) * LDK + kk];
      #pragma unroll
      for (int nt = 0; nt < 8; ++nt)
        bfr[nt] = *(const shortx8*)&Bs[(nt * 16 + lm) * LDK + kk];
      #pragma unroll
      for (int mt = 0; mt < 2; ++mt)
        #pragma unroll
        for (int nt = 0; nt < 8; ++nt)
          acc[mt][nt] = __builtin_amdgcn_mfma_f32_16x16x32_bf16(af[mt], bfr[nt], acc[mt][nt], 0, 0, 0);
    }
  }

  #pragma unroll
  for (int mt = 0; mt < 2; ++mt){
    #pragma unroll
    for (int nt = 0; nt < 8; ++nt){
      #pragma unroll
      for (int i = 0; i < 4; ++i){
        const int ml = w * 32 + mt * 16 + quad * 4 + i;
        const int nl = nt * 16 + lm;
        const int gm = bm * BM + ml;
        const int gn = bn * BN + nl;
        xg[(size_t)gm * G3 + gn] = acc[mt][nt][i] + bih[gn];
      }
    }
  }
}

// ---------------- Phase B: recurrent GRU via MFMA.
// 64 WGs x 256 threads (4 waves, 1 wave/SIMD -> 512-reg budget). B_tile=4
// batch rows (padded to M=16). Whh bf16 as register-resident B-fragments
// (12 Ntiles x 8 Ktiles x shortx8 = 384 VGPRs/lane). Per step:
//   hg = h(bf16, LDS A-frag layout) x WhhT  via 96 MFMA per wave,
//   quad0 lanes dump hg to LDS hgT[col][m], barrier,
//   thread j computes gates for (m=0..3, j) in fp32 (h master in regs),
//   writes bf16 h back into the A-frag buffer, barrier.
__global__ __launch_bounds__(256, 1) void gru_mfma(
    const float* __restrict__ xg, const float* __restrict__ Whh,
    const float* __restrict__ bhh, float* __restrict__ hstate,
    int Tc, int initFlag)
{
  __shared__ alignas(16) unsigned short afrag[8 * 64 * 8];  // [kt][lane][8] bf16, 8 KB
  __shared__ alignas(16) float hgT[G3 * 4];                  // [col][m], 12 KB

  const int tid  = threadIdx.x;
  const int w    = tid >> 6;
  const int l    = tid & 63;
  const int lm   = l & 15;
  const int quad = l >> 4;
  const int b0   = blockIdx.x * 4;

  // B-fragments of WhhT: lane holds Whh[col][k0..k0+7], col = w*192+nt*16+lm,
  // k0 = kt*32 + quad*8.  (matches the layout verified in gemm_xg)
  shortx8 Wf[12][8];
  #pragma unroll
  for (int nt = 0; nt < 12; ++nt){
    const int col = w * 192 + nt * 16 + lm;
    #pragma unroll
    for (int kt = 0; kt < 8; ++kt){
      const int k0 = kt * 32 + quad * 8;
      const float4 v0 = *(const float4*)(Whh + (size_t)col * HID + k0);
      const float4 v1 = *(const float4*)(Whh + (size_t)col * HID + k0 + 4);
      shortx8 f;
      f[0] = (short)f2bf(v0.x); f[1] = (short)f2bf(v0.y);
      f[2] = (short)f2bf(v0.z); f[3] = (short)f2bf(v0.w);
      f[4] = (short)f2bf(v1.x); f[5] = (short)f2bf(v1.y);
      f[6] = (short)f2bf(v1.z); f[7] = (short)f2bf(v1.w);
      Wf[nt][kt] = f;
    }
  }

  const float br = bhh[tid];
  const float bz = bhh[tid + 256];
  const float bn = bhh[tid + 512];

  // Zero the A-frag buffer (also establishes zero padding rows m=4..15).
  {
    uint32_t* p = (uint32_t*)afrag;
    #pragma unroll
    for (int i = 0; i < 8; ++i) p[tid + 256 * i] = 0u;
  }

  float hj[4];
  if (initFlag){
    #pragma unroll
    for (int m = 0; m < 4; ++m) hj[m] = 0.f;
    __syncthreads();
  } else {
    __syncthreads();
    #pragma unroll
    for (int m = 0; m < 4; ++m){
      hj[m] = hstate[(size_t)(b0 + m) * HID + tid];
      afrag[(tid >> 5) * 512 + (((tid >> 3) & 3) * 16 + m) * 8 + (tid & 7)] = f2bf(hj[m]);
    }
    __syncthreads();
  }

  const float* xp[4];
  #pragma unroll
  for (int m = 0; m < 4; ++m)
    xp[m] = xg + (size_t)(b0 + m) * Tc * G3 + tid;

  // Prefetch xg for t=0.
  float pxr[4], pxz[4], pxn[4];
  #pragma unroll
  for (int m = 0; m < 4; ++m){
    pxr[m] = xp[m][0]; pxz[m] = xp[m][256]; pxn[m] = xp[m][512];
  }

  #pragma unroll 1
  for (int t = 0; t < Tc; ++t){
    floatx4 acc[12];
    #pragma unroll
    for (int nt = 0; nt < 12; ++nt) acc[nt] = (floatx4){0.f, 0.f, 0.f, 0.f};

    #pragma unroll
    for (int kt = 0; kt < 8; ++kt){
      const shortx8 A = *(const shortx8*)&afrag[kt * 512 + l * 8];
      #pragma unroll
      for (int nt = 0; nt < 12; ++nt)
        acc[nt] = __builtin_amdgcn_mfma_f32_16x16x32_bf16(A, Wf[nt][kt], acc[nt], 0, 0, 0);
    }

    // Real hg rows (m=0..3) live in quad 0 lanes (C-layout row = quad*4+reg).
    if (quad == 0){
      #pragma unroll
      for (int nt = 0; nt < 12; ++nt){
        const int col = w * 192 + nt * 16 + lm;
        *(floatx4*)&hgT[col * 4] = acc[nt];
      }
    }
    __syncthreads();

    const floatx4 gr = *(const floatx4*)&hgT[tid * 4];
    const floatx4 gz = *(const floatx4*)&hgT[(tid + 256) * 4];
    const floatx4 gn = *(const floatx4*)&hgT[(tid + 512) * 4];

    #pragma unroll
    for (int m = 0; m < 4; ++m){
      const float r = 1.f / (1.f + __expf(-(pxr[m] + gr[m] + br)));
      const float z = 1.f / (1.f + __expf(-(pxz[m] + gz[m] + bz)));
      const float a = pxn[m] + r * (gn[m] + bn);   // b_hh_n inside r* (PyTorch GRU)
      const float ex = __expf(-2.f * fabsf(a));
      float n = (1.f - ex) / (1.f + ex);
      n = copysignf(n, a);
      hj[m] = fmaf(z, hj[m] - n, n);               // (1-z)*n + z*h
      afrag[(tid >> 5) * 512 + (((tid >> 3) & 3) * 16 + m) * 8 + (tid & 7)] = f2bf(hj[m]);
    }

    // Prefetch next step's xg (in flight across barrier + next MFMA phase).
    {
      const int tn = (t + 1 < Tc) ? (t + 1) : t;
      #pragma unroll
      for (int m = 0; m < 4; ++m){
        const float* q = xp[m] + (size_t)tn * G3;
        pxr[m] = q[0]; pxz[m] = q[256]; pxn[m] = q[512];
      }
    }
    __syncthreads();
  }

  #pragma unroll
  for (int m = 0; m < 4; ++m)
    hstate[(size_t)(b0 + m) * HID + tid] = hj[m];
}

// ---------------- FC
__global__ __launch_bounds__(128) void fc_kernel(
    const float* __restrict__ hstate, const float* __restrict__ fw,
    const float* __restrict__ fb, float* __restrict__ out)
{
  __shared__ float hs[HID];
  const int b = blockIdx.x;
  const int t = threadIdx.x;
  hs[t]       = hstate[b * HID + t];
  hs[t + 128] = hstate[b * HID + t + 128];
  __syncthreads();
  if (t < NC){
    float acc = fb[t];
    const float4* w4 = (const float4*)(fw + (size_t)t * HID);
    const float4* h4 = (const float4*)hs;
    #pragma unroll
    for (int k = 0; k < 64; ++k){
      const float4 wv = w4[k];
      const float4 hv = h4[k];
      acc += wv.x * hv.x + wv.y * hv.y + wv.z * hv.z + wv.w * hv.w;
    }
    out[b * NC + t] = acc;
  }
}

extern "C" void kernel_launch(void* const* d_in, const int* in_sizes, int n_in,
                              void* d_out, int out_size, void* d_ws, size_t ws_size,
                              hipStream_t stream)
{
  const float* x   = (const float*)d_in[0];
  const float* Wih = (const float*)d_in[1];
  const float* Whh = (const float*)d_in[2];
  const float* bih = (const float*)d_in[3];
  const float* bhh = (const float*)d_in[4];
  const float* fcw = (const float*)d_in[5];
  const float* fcb = (const float*)d_in[6];
  float* out = (float*)d_out;

  float* hst = (float*)d_ws;
  const size_t hBytes = (size_t)BATCH * HID * sizeof(float);
  float* xg  = (float*)((char*)d_ws + hBytes);

  const size_t perT = (size_t)BATCH * G3 * sizeof(float);
  const size_t avail = (ws_size > hBytes) ? (ws_size - hBytes) : 0;
  int tcLog2 = 9;
  while (tcLog2 > 0 && perT * ((size_t)1 << tcLog2) > avail) --tcLog2;
  const int Tc = 1 << tcLog2;

  for (int t0 = 0; t0 < T_SEQ; t0 += Tc){
    dim3 grid(6, 2 * Tc);
    gemm_xg<<<grid, 256, 0, stream>>>(x, Wih, bih, xg, t0, tcLog2);
    gru_mfma<<<64, 256, 0, stream>>>(xg, Whh, bhh, hst, Tc, (t0 == 0) ? 1 : 0);
  }
  fc_kernel<<<BATCH, 128, 0, stream>>>(hst, fcw, fcb, out);
}